// Round 8
// baseline (292.948 us; speedup 1.0000x reference)
//
#include <hip/hip_runtime.h>
#include <hip/hip_bf16.h>

#define QKVC   2304
#define NHEAD  12
#define NTOK   577
#define NBATCH 16
#define NROWS  (NBATCH * NTOK)   // 9232
#define NPAD   640
#define SCALE  0.125f
#define EPSV   1e-6f
#define LSTR   36                // LDS row stride (u16) = 72B: frag reads exact 2-way (free)

typedef __bf16  bf16x8 __attribute__((ext_vector_type(8)));
typedef float   f32x4  __attribute__((ext_vector_type(4)));

__device__ __forceinline__ unsigned short f2bf(float f) {
    union { float f; unsigned u; } v; v.f = f;
    unsigned r = v.u + 0x7FFFu + ((v.u >> 16) & 1u);   // RNE
    return (unsigned short)(r >> 16);
}
__device__ __forceinline__ unsigned short f2bf_trunc(float f) {
    return (unsigned short)(__float_as_uint(f) >> 16);  // e>=0 only
}
__device__ __forceinline__ f32x4 mfma16(bf16x8 a, bf16x8 b, f32x4 c) {
    return __builtin_amdgcn_mfma_f32_16x16x32_bf16(a, b, c, 0, 0, 0);
}

// ------------------------------------- merged prep: x->bf16 + both W^T
__device__ void transpose_tile(const float* __restrict__ src, unsigned short* __restrict__ dst,
                               int K, int N, int bx, int by, int t) {
    __shared__ unsigned short lt[64 * 72];
    int n0 = bx * 64, k0 = by * 64;
    int kk = t >> 4, nn = (t & 15) * 4;
    for (int i = 0; i < 4; i++) {
        int kr = kk + i * 16;
        float4 v = *(const float4*)&src[(size_t)(k0 + kr) * N + n0 + nn];
        lt[(nn + 0) * 72 + kr] = f2bf(v.x);
        lt[(nn + 1) * 72 + kr] = f2bf(v.y);
        lt[(nn + 2) * 72 + kr] = f2bf(v.z);
        lt[(nn + 3) * 72 + kr] = f2bf(v.w);
    }
    __syncthreads();
    int n = t >> 2, seg = (t & 3) * 16;
    uint4 a = *(uint4*)&lt[n * 72 + seg];
    uint4 b = *(uint4*)&lt[n * 72 + seg + 8];
    *(uint4*)&dst[(size_t)(n0 + n) * K + k0 + seg]     = a;
    *(uint4*)&dst[(size_t)(n0 + n) * K + k0 + seg + 8] = b;
}

#define NCONV (NROWS * 768 / 4 / 256)   // 6927 convert blocks
__global__ void k_prep(const float* __restrict__ x, unsigned short* __restrict__ xb,
                       const float* __restrict__ Wqkv, unsigned short* __restrict__ wqkvt,
                       const float* __restrict__ Wproj, unsigned short* __restrict__ wprojt) {
    int id = blockIdx.x, t = threadIdx.x;
    if (id < NCONV) {
        int idx = id * 256 + t;
        float4 v = ((const float4*)x)[idx];
        ushort4 o;
        o.x = f2bf(v.x); o.y = f2bf(v.y); o.z = f2bf(v.z); o.w = f2bf(v.w);
        ((ushort4*)xb)[idx] = o;
    } else if (id < NCONV + 432) {
        int i2 = id - NCONV;                    // qkv W^T: 36 x 12
        transpose_tile(Wqkv, wqkvt, 768, QKVC, i2 % 36, i2 / 36, t);
    } else {
        int i2 = id - NCONV - 432;              // proj W^T: 12 x 12
        transpose_tile(Wproj, wprojt, 768, 768, i2 % 12, i2 / 12, t);
    }
}

// -------------------------------------------------- 128x128 GEMM, K=768
// MANUAL staging (global->VGPR dwordx4 then ds_write_b128) instead of
// global_load_lds: the glds DMA's LDS-fill throughput (~30B/cyc/CU) was the
// binder (57us for both gemms regardless of pipeline structure; conflict
// counter invariant to read swizzle => counts DMA serialization).
// Pipeline per iter: lgkm(0)+s_barrier (NO vmcnt drain) | issue kt+2 loads
// to regs | ds_read frags + MFMA from buf[kt&1] | vmcnt(4) (kt+1 arrived,
// kt+2 stays in flight) | ds_write kt+1 -> buf[(kt+1)&1].
template <bool F32OUT>
__global__ __launch_bounds__(256, 3)
void k_gemm(const unsigned short* __restrict__ A, const unsigned short* __restrict__ B,
            const float* __restrict__ bias, void* __restrict__ outp, int Ncols) {
    __shared__ unsigned short SL[2][2][128 * LSTR];   // [buf][A/B]: 36,864B total
    int t = threadIdx.x;
    int lane = t & 63, wave = t >> 6, quad = lane >> 4, l15 = lane & 15;
    int wm = wave >> 1, wn = wave & 1;
    int nT = Ncols >> 7;
    int mLocal = blockIdx.x & 7;                  // XCD-stripe mapping (keep)
    int rest = blockIdx.x >> 3;
    int n0 = (rest % nT) * 128;
    int m0 = ((rest / nT) * 8 + mLocal) * 128;

    int srow = wave * 32 + (lane >> 2);           // staging row 0..127 (j=0), +16 (j=1)
    int schk = (lane & 3) * 8;                    // u16 chunk in row
    const unsigned short* gA = A + (size_t)(m0 + srow) * 768 + schk;
    const unsigned short* gB = B + (size_t)(n0 + srow) * 768 + schk;
    int w0 = srow * LSTR + schk, w1 = (srow + 16) * LSTR + schk;

    f32x4 acc[4][4] = {};
    uint4 s0[4], s1[4];
    // prologue: kt0 -> s0, kt1 -> s1, write kt0 to buf0
    s0[0] = *(const uint4*)(gA);      s0[1] = *(const uint4*)(gA + 16 * 768);
    s0[2] = *(const uint4*)(gB);      s0[3] = *(const uint4*)(gB + 16 * 768);
    s1[0] = *(const uint4*)(gA + 32); s1[1] = *(const uint4*)(gA + 16 * 768 + 32);
    s1[2] = *(const uint4*)(gB + 32); s1[3] = *(const uint4*)(gB + 16 * 768 + 32);
    *(uint4*)&SL[0][0][w0] = s0[0];   *(uint4*)&SL[0][0][w1] = s0[1];
    *(uint4*)&SL[0][1][w0] = s0[2];   *(uint4*)&SL[0][1][w1] = s0[3];

    auto body = [&](int kt, uint4* sc, uint4* sw) {
        asm volatile("s_waitcnt lgkmcnt(0)" ::: "memory");   // our ds_writes visible
        asm volatile("s_barrier" ::: "memory");              // buf[kt&1] ready everywhere
        int buf = kt & 1;
        if (kt < 22) {                                       // prefetch kt+2 into freed set
            int ko = (kt + 2) * 32;
            sc[0] = *(const uint4*)(gA + ko); sc[1] = *(const uint4*)(gA + 16 * 768 + ko);
            sc[2] = *(const uint4*)(gB + ko); sc[3] = *(const uint4*)(gB + 16 * 768 + ko);
        }
        bf16x8 af[4], bfr[4];
        for (int i = 0; i < 4; i++) {
            af[i]  = *(const bf16x8*)&SL[buf][0][(wm * 64 + i * 16 + l15) * LSTR + quad * 8];
            bfr[i] = *(const bf16x8*)&SL[buf][1][(wn * 64 + i * 16 + l15) * LSTR + quad * 8];
        }
        for (int mi = 0; mi < 4; mi++)
            for (int ni = 0; ni < 4; ni++)
                acc[mi][ni] = mfma16(af[mi], bfr[ni], acc[mi][ni]);
        if (kt < 23) {                                       // stage kt+1 into other buf
            if (kt >= 22) asm volatile("s_waitcnt vmcnt(0)" ::: "memory");
            else          asm volatile("s_waitcnt vmcnt(4)" ::: "memory");
            int nb = buf ^ 1;
            *(uint4*)&SL[nb][0][w0] = sw[0]; *(uint4*)&SL[nb][0][w1] = sw[1];
            *(uint4*)&SL[nb][1][w0] = sw[2]; *(uint4*)&SL[nb][1][w1] = sw[3];
        }
    };
    for (int k2 = 0; k2 < 12; k2++) {            // unrolled x2: set roles static
        body(2 * k2,     s0, s1);
        body(2 * k2 + 1, s1, s0);
    }

    if constexpr (F32OUT) {
        for (int ni = 0; ni < 4; ni++) {
            int col = n0 + wn * 64 + ni * 16 + l15;
            float bv = bias[col];
            for (int mi = 0; mi < 4; mi++) {
                int rowm = m0 + wm * 64 + mi * 16 + quad * 4;
                for (int r = 0; r < 4; r++) {
                    int m = rowm + r;
                    if (m < NROWS)
                        ((float*)outp)[(size_t)m * Ncols + col] = acc[mi][ni][r] + bv;
                }
            }
        }
    } else {
        // repack 128x128 bf16 tile through LDS (stride 132 u16, 33.8KB <= 36.9KB)
        unsigned short* RP = (unsigned short*)SL;
        __syncthreads();
        for (int ni = 0; ni < 4; ni++) {
            int colL = wn * 64 + ni * 16 + l15;
            float bv = bias[n0 + colL];
            for (int mi = 0; mi < 4; mi++) {
                int rowL = wm * 64 + mi * 16 + quad * 4;
                for (int r = 0; r < 4; r++)
                    RP[(rowL + r) * 132 + colL] = f2bf(acc[mi][ni][r] + bv);
            }
        }
        __syncthreads();
        for (int rr = 0; rr < 8; rr++) {
            int row = rr * 16 + (t >> 4);
            int m = m0 + row;
            if (m < NROWS) {
                uint4 v = *(uint4*)&RP[row * 132 + (t & 15) * 8];
                *(uint4*)&((unsigned short*)outp)[(size_t)m * Ncols + n0 + (t & 15) * 8] = v;
            }
        }
    }
}

// -------------------------------------------- V slice of qkv -> V^T [d][tok]
__global__ void k_vtrans(const unsigned short* __restrict__ qkv, unsigned short* __restrict__ vt) {
    __shared__ unsigned short lt[64 * 72];
    int t = threadIdx.x;
    int b = blockIdx.z, h = blockIdx.y, tt = blockIdx.x;
    for (int i = t; i < 512; i += 256) {
        int row = i >> 3, seg = (i & 7) * 8;
        int tok = tt * 64 + row;
        uint4 v = {0, 0, 0, 0};
        if (tok < NTOK)
            v = *(const uint4*)&qkv[(size_t)(b * NTOK + tok) * QKVC + 1536 + h * 64 + seg];
        *(uint4*)&lt[row * 72 + seg] = v;
    }
    __syncthreads();
    for (int i = t; i < 512; i += 256) {
        int d = i >> 3, ts = i & 7;
        unsigned short tmp[8];
        for (int j = 0; j < 8; j++) tmp[j] = lt[(ts * 8 + j) * 72 + d];
        *(uint4*)&vt[((size_t)((b * NHEAD + h) * 64) + d) * NPAD + tt * 64 + ts * 8] =
            *(uint4*)tmp;
    }
}

// --------------------------------------------------------- flash attention
__global__ __launch_bounds__(256, 4)
void k_attn(const unsigned short* __restrict__ qkv, const unsigned short* __restrict__ vt,
            const float* __restrict__ policy, unsigned short* __restrict__ ao) {
    __shared__ unsigned short Ks[64 * 72];
    __shared__ unsigned short Vs[64 * 72];
    __shared__ unsigned short Ps[4][32 * 72];
    __shared__ float pol[NPAD];
    int t = threadIdx.x;
    int lane = t & 63, wave = t >> 6, quad = lane >> 4, l15 = lane & 15;
    int b = blockIdx.z, h = blockIdx.y, qt = blockIdx.x;
    const unsigned short* qbase = qkv + (size_t)(b * NTOK) * QKVC + h * 64;
    const unsigned short* kbase = qkv + (size_t)(b * NTOK) * QKVC + 768 + h * 64;
    const unsigned short* vbase = vt + (size_t)(b * NHEAD + h) * 64 * NPAD;

    for (int i = t; i < NPAD; i += 256)
        pol[i] = (i < NTOK) ? policy[b * NTOK + i] : 0.f;

    bf16x8 qf[2][2];
    for (int mi = 0; mi < 2; mi++) {
        const unsigned short* qp =
            qbase + (size_t)(qt * 128 + mi * 64 + wave * 16 + l15) * QKVC + quad * 8;
        qf[mi][0] = *(const bf16x8*)qp;
        qf[mi][1] = *(const bf16x8*)(qp + 32);
    }
    bf16x8 onesf;
    for (int j = 0; j < 8; j++) onesf[j] = (__bf16)1.0f;
    f32x4 o[2][4] = {};
    f32x4 ls[2] = {};
    int rowtok0[2];
    for (int mi = 0; mi < 2; mi++)
        rowtok0[mi] = qt * 128 + mi * 64 + wave * 16 + quad * 4;
    __syncthreads();

    for (int kt = 0; kt < 10; kt++) {
        int key0 = kt * 64;
        for (int i = t; i < 512; i += 256) {
            int row = i >> 3, seg = (i & 7) * 8;
            *(uint4*)&Ks[row * 72 + seg] = *(const uint4*)&kbase[(size_t)(key0 + row) * QKVC + seg];
            *(uint4*)&Vs[row * 72 + seg] = *(const uint4*)&vbase[(size_t)row * NPAD + key0 + seg];
        }
        __syncthreads();

        for (int ci = 0; ci < 4; ci++) {
            bf16x8 kf0 = *(const bf16x8*)&Ks[(ci * 16 + l15) * 72 + quad * 8];
            bf16x8 kf1 = *(const bf16x8*)&Ks[(ci * 16 + l15) * 72 + 32 + quad * 8];
            int col = key0 + ci * 16 + l15;
            float pc = pol[col];
            for (int mi = 0; mi < 2; mi++) {
                f32x4 a = {};
                a = mfma16(qf[mi][0], kf0, a);
                a = mfma16(qf[mi][1], kf1, a);
                for (int r = 0; r < 4; r++) {
                    float ap = (col == rowtok0[mi] + r) ? 1.f : pc;
                    float e = __expf(a[r] * SCALE) * ap;
                    Ps[wave][(mi * 16 + quad * 4 + r) * 72 + ci * 16 + l15] = f2bf_trunc(e);
                }
            }
        }
        __asm__ volatile("s_waitcnt lgkmcnt(0)" ::: "memory");
        bf16x8 pf[2][2];
        for (int mi = 0; mi < 2; mi++) {
            pf[mi][0] = *(const bf16x8*)&Ps[wave][(mi * 16 + l15) * 72 + quad * 8];
            pf[mi][1] = *(const bf16x8*)&Ps[wave][(mi * 16 + l15) * 72 + 32 + quad * 8];
            ls[mi] = mfma16(pf[mi][0], onesf, ls[mi]);
            ls[mi] = mfma16(pf[mi][1], onesf, ls[mi]);
        }
        for (int di = 0; di < 4; di++) {
            bf16x8 vf0 = *(const bf16x8*)&Vs[(di * 16 + l15) * 72 + quad * 8];
            bf16x8 vf1 = *(const bf16x8*)&Vs[(di * 16 + l15) * 72 + 32 + quad * 8];
            for (int mi = 0; mi < 2; mi++) {
                o[mi][di] = mfma16(pf[mi][0], vf0, o[mi][di]);
                o[mi][di] = mfma16(pf[mi][1], vf1, o[mi][di]);
            }
        }
        __syncthreads();
    }

    for (int mi = 0; mi < 2; mi++) {
        for (int r = 0; r < 4; r++) {
            int tok = rowtok0[mi] + r;
            if (tok < NTOK) {
                float inv = __builtin_amdgcn_rcpf(ls[mi][r] + EPSV);
                for (int di = 0; di < 4; di++) {
                    float val = o[mi][di][r] * inv;
                    ao[((size_t)(b * NTOK + tok)) * 768 + h * 64 + di * 16 + l15] = f2bf(val);
                }
            }
        }
    }
}

// ------------------------------------------------------------------ launch
extern "C" void kernel_launch(void* const* d_in, const int* in_sizes, int n_in,
                              void* d_out, int out_size, void* d_ws, size_t ws_size,
                              hipStream_t stream) {
    const float* x      = (const float*)d_in[0];
    const float* policy = (const float*)d_in[1];
    const float* Wqkv   = (const float*)d_in[2];
    const float* bqkv   = (const float*)d_in[3];
    const float* Wproj  = (const float*)d_in[4];
    const float* bproj  = (const float*)d_in[5];
    float* out = (float*)d_out;

    // workspace carve. xb/ao alias (xb dead before ao written). GEMM A-staging
    // over-reads up to ~1.5MB past xb/ao end (absorbed by wqkvt+wprojt).
    // Attention over-reads <=300KB past qkvb (absorbed by vt).
    unsigned short* p = (unsigned short*)d_ws;
    unsigned short* xb     = p;
    unsigned short* ao     = p; p += (size_t)NROWS * 768;
    unsigned short* wqkvt  = p; p += (size_t)QKVC * 768;
    unsigned short* wprojt = p; p += (size_t)768 * 768;
    unsigned short* qkvb   = p; p += (size_t)NROWS * QKVC;
    unsigned short* vt     = p; p += (size_t)NBATCH * NHEAD * 64 * NPAD;

    int mT = (NROWS + 127) / 128;   // 73
    int mG = (mT + 7) / 8;          // 10 groups of 8 m-tiles (XCD stripes)

    k_prep<<<NCONV + 432 + 144, 256, 0, stream>>>(x, xb, Wqkv, wqkvt, Wproj, wprojt);
    k_gemm<false><<<mG * 8 * (QKVC / 128), 256, 0, stream>>>(
        xb, wqkvt, bqkv, (void*)qkvb, QKVC);
    k_vtrans<<<dim3(NPAD / 64, NHEAD, NBATCH), 256, 0, stream>>>(qkvb, vt);
    k_attn<<<dim3(NPAD / 128, NHEAD, NBATCH), 256, 0, stream>>>(qkvb, vt, policy, ao);
    k_gemm<true><<<mG * 8 * (768 / 128), 256, 0, stream>>>(
        ao, wprojt, bproj, (void*)out, 768);
}

// Round 9
// 205.057 us; speedup vs baseline: 1.4286x; 1.4286x over previous
//
#include <hip/hip_runtime.h>
#include <hip/hip_bf16.h>

#define QKVC   2304
#define NHEAD  12
#define NTOK   577
#define NBATCH 16
#define NROWS  (NBATCH * NTOK)   // 9232
#define NPAD   640
#define SCALE  0.125f
#define EPSV   1e-6f

typedef __bf16  bf16x8 __attribute__((ext_vector_type(8)));
typedef float   f32x4  __attribute__((ext_vector_type(4)));

__device__ __forceinline__ unsigned short f2bf(float f) {
    union { float f; unsigned u; } v; v.f = f;
    unsigned r = v.u + 0x7FFFu + ((v.u >> 16) & 1u);   // RNE
    return (unsigned short)(r >> 16);
}
__device__ __forceinline__ unsigned short f2bf_trunc(float f) {
    return (unsigned short)(__float_as_uint(f) >> 16);  // e>=0 only
}
__device__ __forceinline__ f32x4 mfma16(bf16x8 a, bf16x8 b, f32x4 c) {
    return __builtin_amdgcn_mfma_f32_16x16x32_bf16(a, b, c, 0, 0, 0);
}

// async global->LDS, 16B/lane; LDS dest = wave-uniform base + lane*16
#define GLDS16(g, l) __builtin_amdgcn_global_load_lds( \
    (const __attribute__((address_space(1))) unsigned int*)(g), \
    (__attribute__((address_space(3))) unsigned int*)(l), 16, 0, 0)

// ------------------------------------- merged prep: x->bf16 + both W^T
__device__ void transpose_tile(const float* __restrict__ src, unsigned short* __restrict__ dst,
                               int K, int N, int bx, int by, int t) {
    __shared__ unsigned short lt[64 * 72];
    int n0 = bx * 64, k0 = by * 64;
    int kk = t >> 4, nn = (t & 15) * 4;
    for (int i = 0; i < 4; i++) {
        int kr = kk + i * 16;
        float4 v = *(const float4*)&src[(size_t)(k0 + kr) * N + n0 + nn];
        lt[(nn + 0) * 72 + kr] = f2bf(v.x);
        lt[(nn + 1) * 72 + kr] = f2bf(v.y);
        lt[(nn + 2) * 72 + kr] = f2bf(v.z);
        lt[(nn + 3) * 72 + kr] = f2bf(v.w);
    }
    __syncthreads();
    int n = t >> 2, seg = (t & 3) * 16;
    uint4 a = *(uint4*)&lt[n * 72 + seg];
    uint4 b = *(uint4*)&lt[n * 72 + seg + 8];
    *(uint4*)&dst[(size_t)(n0 + n) * K + k0 + seg]     = a;
    *(uint4*)&dst[(size_t)(n0 + n) * K + k0 + seg + 8] = b;
}

#define NCONV (NROWS * 768 / 4 / 256)   // 6927 convert blocks
__global__ void k_prep(const float* __restrict__ x, unsigned short* __restrict__ xb,
                       const float* __restrict__ Wqkv, unsigned short* __restrict__ wqkvt,
                       const float* __restrict__ Wproj, unsigned short* __restrict__ wprojt) {
    int id = blockIdx.x, t = threadIdx.x;
    if (id < NCONV) {
        int idx = id * 256 + t;
        float4 v = ((const float4*)x)[idx];
        ushort4 o;
        o.x = f2bf(v.x); o.y = f2bf(v.y); o.z = f2bf(v.z); o.w = f2bf(v.w);
        ((ushort4*)xb)[idx] = o;
    } else if (id < NCONV + 432) {
        int i2 = id - NCONV;                    // qkv W^T: 36 x 12
        transpose_tile(Wqkv, wqkvt, 768, QKVC, i2 % 36, i2 / 36, t);
    } else {
        int i2 = id - NCONV - 432;              // proj W^T: 12 x 12
        transpose_tile(Wproj, wprojt, 768, 768, i2 % 12, i2 / 12, t);
    }
}

// -------------------------------------------------- 128x128 GEMM, K=768
// R6-proven loop: XCD-stripe 1D grid; triple-buffered LDS + glds width16;
// s_waitcnt vmcnt(4) raw-barrier pipeline (2-iter prefetch, never drains to 0
// until last iter). glds staging costs ZERO VGPRs (R8's manual staging
// spilled: VGPR=64 with 96+ demand -> scratch traffic, 2x regression).
// bf16 epilogue: LDS repack; Q/K tiles (n0<1536) -> full-line row stores to
// qkvb; V tiles (n0>=1536) -> TRANSPOSED scalar stores direct to vt
// (lanes walk consecutive tokens -> coalesced 128B runs; replaces k_vtrans).
template <bool F32OUT>
__global__ __launch_bounds__(256, 3)
void k_gemm(const unsigned short* __restrict__ A, const unsigned short* __restrict__ B,
            const float* __restrict__ bias, void* __restrict__ outp, int Ncols,
            unsigned short* __restrict__ vt) {
    __shared__ unsigned short SL[24576];   // 48KB: 3x(As+Bs); epilogue repack
    unsigned short (*As)[4096] = (unsigned short (*)[4096])SL;
    unsigned short (*Bs)[4096] = (unsigned short (*)[4096])&SL[12288];
    int t = threadIdx.x;
    int lane = t & 63, wave = t >> 6, quad = lane >> 4, l15 = lane & 15;
    int wm = wave >> 1, wn = wave & 1;
    int nT = Ncols >> 7;
    int mLocal = blockIdx.x & 7;                  // XCD-stripe mapping
    int rest = blockIdx.x >> 3;
    int n0 = (rest % nT) * 128;
    int m0 = ((rest / nT) * 8 + mLocal) * 128;

    const unsigned short* ga0 = A + (size_t)(m0 + wave * 32 + (lane >> 2)) * 768 + (lane & 3) * 8;
    const unsigned short* ga1 = ga0 + (size_t)16 * 768;
    const unsigned short* gb0 = B + (size_t)(n0 + wave * 32 + (lane >> 2)) * 768 + (lane & 3) * 8;
    const unsigned short* gb1 = gb0 + (size_t)16 * 768;
    unsigned lo = wave * 1024;   // u16 offset of this wave's 32-row chunk

    f32x4 acc[4][4] = {};

    // prologue: buffers for kt=0,1 (8 glds/wave outstanding)
    GLDS16(ga0,      &As[0][lo]); GLDS16(ga1,      &As[0][lo + 512]);
    GLDS16(gb0,      &Bs[0][lo]); GLDS16(gb1,      &Bs[0][lo + 512]);
    GLDS16(ga0 + 32, &As[1][lo]); GLDS16(ga1 + 32, &As[1][lo + 512]);
    GLDS16(gb0 + 32, &Bs[1][lo]); GLDS16(gb1 + 32, &Bs[1][lo + 512]);

    #pragma unroll 3
    for (int kt = 0; kt < 24; kt++) {
        int buf = kt % 3;
        if (kt == 23) { asm volatile("s_waitcnt vmcnt(0)" ::: "memory"); }
        else          { asm volatile("s_waitcnt vmcnt(4)" ::: "memory"); }
        asm volatile("s_barrier" ::: "memory");
        if (kt < 22) {
            int nb = buf + 2; if (nb >= 3) nb -= 3;
            int ko = (kt + 2) * 32;
            GLDS16(ga0 + ko, &As[nb][lo]); GLDS16(ga1 + ko, &As[nb][lo + 512]);
            GLDS16(gb0 + ko, &Bs[nb][lo]); GLDS16(gb1 + ko, &Bs[nb][lo + 512]);
        }
        bf16x8 af[4], bfr[4];
        for (int i = 0; i < 4; i++) {
            af[i]  = *(const bf16x8*)&As[buf][(wm * 64 + i * 16 + l15) * 32 + quad * 8];
            bfr[i] = *(const bf16x8*)&Bs[buf][(wn * 64 + i * 16 + l15) * 32 + quad * 8];
        }
        for (int mi = 0; mi < 4; mi++)
            for (int ni = 0; ni < 4; ni++)
                acc[mi][ni] = mfma16(af[mi], bfr[ni], acc[mi][ni]);
    }
    asm volatile("" ::: "memory");

    if constexpr (F32OUT) {
        for (int ni = 0; ni < 4; ni++) {
            int col = n0 + wn * 64 + ni * 16 + l15;
            float bv = bias[col];
            for (int mi = 0; mi < 4; mi++) {
                int rowm = m0 + wm * 64 + mi * 16 + quad * 4;
                for (int r = 0; r < 4; r++) {
                    int m = rowm + r;
                    if (m < NROWS)
                        ((float*)outp)[(size_t)m * Ncols + col] = acc[mi][ni][r] + bv;
                }
            }
        }
    } else {
        // repack 128x128 bf16 tile (stride 132 u16) in LDS
        __syncthreads();
        for (int ni = 0; ni < 4; ni++) {
            int colL = wn * 64 + ni * 16 + l15;
            float bv = bias[n0 + colL];
            for (int mi = 0; mi < 4; mi++) {
                int rowL = wm * 64 + mi * 16 + quad * 4;
                for (int r = 0; r < 4; r++)
                    SL[(rowL + r) * 132 + colL] = f2bf(acc[mi][ni][r] + bv);
            }
        }
        __syncthreads();
        if (n0 < 1536) {
            // Q/K cols: full-line row stores to qkvb
            for (int rr = 0; rr < 8; rr++) {
                int row = rr * 16 + (t >> 4);
                int m = m0 + row;
                if (m < NROWS) {
                    uint4 v = *(uint4*)&SL[row * 132 + (t & 15) * 8];
                    *(uint4*)&((unsigned short*)outp)[(size_t)m * Ncols + n0 + (t & 15) * 8] = v;
                }
            }
        } else {
            // V cols: transposed store direct into vt[((b*12+h)*64+d)*NPAD + tok]
            // lanes (= consecutive m = consecutive tok) give coalesced 128B runs.
            int h0 = (n0 - 1536) >> 6;
            for (int i = 0; i < 32; i++) {
                int c = wave * 32 + i;
                int h = h0 + (c >> 6), d = c & 63;
                for (int half = 0; half < 2; half++) {
                    int lr = half * 64 + lane;
                    int m = m0 + lr;
                    if (m < NROWS) {
                        unsigned bb = (unsigned)m / 577u;
                        int tok = m - (int)bb * 577;
                        vt[(((size_t)bb * NHEAD + h) * 64 + d) * NPAD + tok] =
                            SL[lr * 132 + c];
                    }
                }
            }
        }
    }
}

// --------------------------------------------------------- flash attention
// 128 q-rows per block; Q-frags direct global->VGPR; no max-subtraction
// (scores bounded); row-sum via ones-MFMA. Pad-token V is unwritten poison,
// but P==0 exactly there (pol=0, bf16 trunc) so PV is unaffected.
__global__ __launch_bounds__(256, 4)
void k_attn(const unsigned short* __restrict__ qkv, const unsigned short* __restrict__ vt,
            const float* __restrict__ policy, unsigned short* __restrict__ ao) {
    __shared__ unsigned short Ks[64 * 72];
    __shared__ unsigned short Vs[64 * 72];
    __shared__ unsigned short Ps[4][32 * 72];
    __shared__ float pol[NPAD];
    int t = threadIdx.x;
    int lane = t & 63, wave = t >> 6, quad = lane >> 4, l15 = lane & 15;
    int b = blockIdx.z, h = blockIdx.y, qt = blockIdx.x;
    const unsigned short* qbase = qkv + (size_t)(b * NTOK) * QKVC + h * 64;
    const unsigned short* kbase = qkv + (size_t)(b * NTOK) * QKVC + 768 + h * 64;
    const unsigned short* vbase = vt + (size_t)(b * NHEAD + h) * 64 * NPAD;

    for (int i = t; i < NPAD; i += 256)
        pol[i] = (i < NTOK) ? policy[b * NTOK + i] : 0.f;

    bf16x8 qf[2][2];
    for (int mi = 0; mi < 2; mi++) {
        const unsigned short* qp =
            qbase + (size_t)(qt * 128 + mi * 64 + wave * 16 + l15) * QKVC + quad * 8;
        qf[mi][0] = *(const bf16x8*)qp;
        qf[mi][1] = *(const bf16x8*)(qp + 32);
    }
    bf16x8 onesf;
    for (int j = 0; j < 8; j++) onesf[j] = (__bf16)1.0f;
    f32x4 o[2][4] = {};
    f32x4 ls[2] = {};
    int rowtok0[2];
    for (int mi = 0; mi < 2; mi++)
        rowtok0[mi] = qt * 128 + mi * 64 + wave * 16 + quad * 4;
    __syncthreads();

    for (int kt = 0; kt < 10; kt++) {
        int key0 = kt * 64;
        for (int i = t; i < 512; i += 256) {
            int row = i >> 3, seg = (i & 7) * 8;
            *(uint4*)&Ks[row * 72 + seg] = *(const uint4*)&kbase[(size_t)(key0 + row) * QKVC + seg];
            *(uint4*)&Vs[row * 72 + seg] = *(const uint4*)&vbase[(size_t)row * NPAD + key0 + seg];
        }
        __syncthreads();

        for (int ci = 0; ci < 4; ci++) {
            bf16x8 kf0 = *(const bf16x8*)&Ks[(ci * 16 + l15) * 72 + quad * 8];
            bf16x8 kf1 = *(const bf16x8*)&Ks[(ci * 16 + l15) * 72 + 32 + quad * 8];
            int col = key0 + ci * 16 + l15;
            float pc = pol[col];
            for (int mi = 0; mi < 2; mi++) {
                f32x4 a = {};
                a = mfma16(qf[mi][0], kf0, a);
                a = mfma16(qf[mi][1], kf1, a);
                for (int r = 0; r < 4; r++) {
                    float ap = (col == rowtok0[mi] + r) ? 1.f : pc;
                    float e = __expf(a[r] * SCALE) * ap;
                    Ps[wave][(mi * 16 + quad * 4 + r) * 72 + ci * 16 + l15] = f2bf_trunc(e);
                }
            }
        }
        __asm__ volatile("s_waitcnt lgkmcnt(0)" ::: "memory");
        bf16x8 pf[2][2];
        for (int mi = 0; mi < 2; mi++) {
            pf[mi][0] = *(const bf16x8*)&Ps[wave][(mi * 16 + l15) * 72 + quad * 8];
            pf[mi][1] = *(const bf16x8*)&Ps[wave][(mi * 16 + l15) * 72 + 32 + quad * 8];
            ls[mi] = mfma16(pf[mi][0], onesf, ls[mi]);
            ls[mi] = mfma16(pf[mi][1], onesf, ls[mi]);
        }
        for (int di = 0; di < 4; di++) {
            bf16x8 vf0 = *(const bf16x8*)&Vs[(di * 16 + l15) * 72 + quad * 8];
            bf16x8 vf1 = *(const bf16x8*)&Vs[(di * 16 + l15) * 72 + 32 + quad * 8];
            for (int mi = 0; mi < 2; mi++) {
                o[mi][di] = mfma16(pf[mi][0], vf0, o[mi][di]);
                o[mi][di] = mfma16(pf[mi][1], vf1, o[mi][di]);
            }
        }
        __syncthreads();
    }

    for (int mi = 0; mi < 2; mi++) {
        for (int r = 0; r < 4; r++) {
            int tok = rowtok0[mi] + r;
            if (tok < NTOK) {
                float inv = __builtin_amdgcn_rcpf(ls[mi][r] + EPSV);
                for (int di = 0; di < 4; di++) {
                    float val = o[mi][di][r] * inv;
                    ao[((size_t)(b * NTOK + tok)) * 768 + h * 64 + di * 16 + l15] = f2bf(val);
                }
            }
        }
    }
}

// ------------------------------------------------------------------ launch
extern "C" void kernel_launch(void* const* d_in, const int* in_sizes, int n_in,
                              void* d_out, int out_size, void* d_ws, size_t ws_size,
                              hipStream_t stream) {
    const float* x      = (const float*)d_in[0];
    const float* policy = (const float*)d_in[1];
    const float* Wqkv   = (const float*)d_in[2];
    const float* bqkv   = (const float*)d_in[3];
    const float* Wproj  = (const float*)d_in[4];
    const float* bproj  = (const float*)d_in[5];
    float* out = (float*)d_out;

    // workspace carve. xb/ao alias (xb dead before ao written). GEMM A-staging
    // over-reads up to ~1.5MB past xb/ao end (absorbed by wqkvt+wprojt);
    // attention Q/K over-reads <=300KB past qkvb (absorbed by vt).
    unsigned short* p = (unsigned short*)d_ws;
    unsigned short* xb     = p;
    unsigned short* ao     = p; p += (size_t)NROWS * 768;
    unsigned short* wqkvt  = p; p += (size_t)QKVC * 768;
    unsigned short* wprojt = p; p += (size_t)768 * 768;
    unsigned short* qkvb   = p; p += (size_t)NROWS * QKVC;
    unsigned short* vt     = p; p += (size_t)NBATCH * NHEAD * 64 * NPAD;

    int mT = (NROWS + 127) / 128;   // 73
    int mG = (mT + 7) / 8;          // 10 groups of 8 m-tiles (XCD stripes)

    k_prep<<<NCONV + 432 + 144, 256, 0, stream>>>(x, xb, Wqkv, wqkvt, Wproj, wprojt);
    k_gemm<false><<<mG * 8 * (QKVC / 128), 256, 0, stream>>>(
        xb, wqkvt, bqkv, (void*)qkvb, QKVC, vt);
    k_attn<<<dim3(NPAD / 128, NHEAD, NBATCH), 256, 0, stream>>>(qkvb, vt, policy, ao);
    k_gemm<true><<<mG * 8 * (768 / 128), 256, 0, stream>>>(
        ao, wprojt, bproj, (void*)out, 768, nullptr);
}

// Round 10
// 204.040 us; speedup vs baseline: 1.4357x; 1.0050x over previous
//
#include <hip/hip_runtime.h>
#include <hip/hip_bf16.h>

#define QKVC   2304
#define NHEAD  12
#define NTOK   577
#define NBATCH 16
#define NROWS  (NBATCH * NTOK)   // 9232
#define NPAD   640
#define SCALE  0.125f
#define EPSV   1e-6f

typedef __bf16  bf16x8 __attribute__((ext_vector_type(8)));
typedef float   f32x4  __attribute__((ext_vector_type(4)));

__device__ __forceinline__ unsigned short f2bf(float f) {
    union { float f; unsigned u; } v; v.f = f;
    unsigned r = v.u + 0x7FFFu + ((v.u >> 16) & 1u);   // RNE
    return (unsigned short)(r >> 16);
}
__device__ __forceinline__ unsigned short f2bf_trunc(float f) {
    return (unsigned short)(__float_as_uint(f) >> 16);  // e>=0 only
}
__device__ __forceinline__ f32x4 mfma16(bf16x8 a, bf16x8 b, f32x4 c) {
    return __builtin_amdgcn_mfma_f32_16x16x32_bf16(a, b, c, 0, 0, 0);
}

// async global->LDS, 16B/lane; LDS dest = wave-uniform base + lane*16
#define GLDS16(g, l) __builtin_amdgcn_global_load_lds( \
    (const __attribute__((address_space(1))) unsigned int*)(g), \
    (__attribute__((address_space(3))) unsigned int*)(l), 16, 0, 0)

// ------------------------------------- merged prep: x->bf16 + both W^T
__device__ void transpose_tile(const float* __restrict__ src, unsigned short* __restrict__ dst,
                               int K, int N, int bx, int by, int t) {
    __shared__ unsigned short lt[64 * 72];
    int n0 = bx * 64, k0 = by * 64;
    int kk = t >> 4, nn = (t & 15) * 4;
    for (int i = 0; i < 4; i++) {
        int kr = kk + i * 16;
        float4 v = *(const float4*)&src[(size_t)(k0 + kr) * N + n0 + nn];
        lt[(nn + 0) * 72 + kr] = f2bf(v.x);
        lt[(nn + 1) * 72 + kr] = f2bf(v.y);
        lt[(nn + 2) * 72 + kr] = f2bf(v.z);
        lt[(nn + 3) * 72 + kr] = f2bf(v.w);
    }
    __syncthreads();
    int n = t >> 2, seg = (t & 3) * 16;
    uint4 a = *(uint4*)&lt[n * 72 + seg];
    uint4 b = *(uint4*)&lt[n * 72 + seg + 8];
    *(uint4*)&dst[(size_t)(n0 + n) * K + k0 + seg]     = a;
    *(uint4*)&dst[(size_t)(n0 + n) * K + k0 + seg + 8] = b;
}

#define NCONV (NROWS * 768 / 4 / 256)   // 6927 convert blocks
__global__ void k_prep(const float* __restrict__ x, unsigned short* __restrict__ xb,
                       const float* __restrict__ Wqkv, unsigned short* __restrict__ wqkvt,
                       const float* __restrict__ Wproj, unsigned short* __restrict__ wprojt) {
    int id = blockIdx.x, t = threadIdx.x;
    if (id < NCONV) {
        int idx = id * 256 + t;
        float4 v = ((const float4*)x)[idx];
        ushort4 o;
        o.x = f2bf(v.x); o.y = f2bf(v.y); o.z = f2bf(v.z); o.w = f2bf(v.w);
        ((ushort4*)xb)[idx] = o;
    } else if (id < NCONV + 432) {
        int i2 = id - NCONV;                    // qkv W^T: 36 x 12
        transpose_tile(Wqkv, wqkvt, 768, QKVC, i2 % 36, i2 / 36, t);
    } else {
        int i2 = id - NCONV - 432;              // proj W^T: 12 x 12
        transpose_tile(Wproj, wprojt, 768, 768, i2 % 12, i2 / 12, t);
    }
}

// -------------------------------------------------- 128x128 GEMM, K=768
// BK=64 EXPERIMENT: halve the barrier count (24->12), double MFMA-per-barrier
// (16->32). Each 64-K buffer is two stacked BK=32 sub-tiles so the proven
// glds pattern & fragment addressing are unchanged. Double-buffered (64KB,
// 2 blocks/CU), 1-iter prefetch issued right after the barrier (target buf
// was freed by that barrier). Same total glds/bytes as BK=32 -- the ONLY
// variables are barrier cadence and occupancy 3->2. Discriminates the
// per-barrier-convergence-overhead theory of the 2900cyc/iter stall.
template <bool F32OUT>
__global__ __launch_bounds__(256, 2)
void k_gemm(const unsigned short* __restrict__ A, const unsigned short* __restrict__ B,
            const float* __restrict__ bias, void* __restrict__ outp, int Ncols,
            unsigned short* __restrict__ vt) {
    __shared__ unsigned short SL[32768];   // 64KB: A[2buf][2half][4096] | B same @16384
    int t = threadIdx.x;
    int lane = t & 63, wave = t >> 6, quad = lane >> 4, l15 = lane & 15;
    int wm = wave >> 1, wn = wave & 1;
    int nT = Ncols >> 7;
    int mLocal = blockIdx.x & 7;                  // XCD-stripe mapping
    int rest = blockIdx.x >> 3;
    int n0 = (rest % nT) * 128;
    int m0 = ((rest / nT) * 8 + mLocal) * 128;

    const unsigned short* ga0 = A + (size_t)(m0 + wave * 32 + (lane >> 2)) * 768 + (lane & 3) * 8;
    const unsigned short* ga1 = ga0 + (size_t)16 * 768;
    const unsigned short* gb0 = B + (size_t)(n0 + wave * 32 + (lane >> 2)) * 768 + (lane & 3) * 8;
    const unsigned short* gb1 = gb0 + (size_t)16 * 768;
    unsigned lo = wave * 1024;   // u16 offset of this wave's 32-row chunk

    f32x4 acc[4][4] = {};

    // prologue: kt=0 buffer (both halves), 8 glds/wave outstanding
    GLDS16(ga0,      &SL[lo]);              GLDS16(ga1,      &SL[lo + 512]);
    GLDS16(ga0 + 32, &SL[4096 + lo]);       GLDS16(ga1 + 32, &SL[4096 + lo + 512]);
    GLDS16(gb0,      &SL[16384 + lo]);      GLDS16(gb1,      &SL[16384 + lo + 512]);
    GLDS16(gb0 + 32, &SL[20480 + lo]);      GLDS16(gb1 + 32, &SL[20480 + lo + 512]);

    #pragma unroll 2
    for (int kt = 0; kt < 12; kt++) {
        unsigned ab = (kt & 1) * 8192;            // this iter's A buf base
        unsigned bb = 16384 + ab;
        asm volatile("s_waitcnt vmcnt(0)" ::: "memory");   // kt's 8 glds done
        asm volatile("s_barrier" ::: "memory");            // buf ready everywhere
        if (kt < 11) {                                     // prefetch kt+1 -> other buf
            unsigned na = 8192 - ab, nb = 16384 + na;
            int ko = (kt + 1) * 64;
            GLDS16(ga0 + ko,      &SL[na + lo]);        GLDS16(ga1 + ko,      &SL[na + lo + 512]);
            GLDS16(ga0 + ko + 32, &SL[na + 4096 + lo]); GLDS16(ga1 + ko + 32, &SL[na + 4096 + lo + 512]);
            GLDS16(gb0 + ko,      &SL[nb + lo]);        GLDS16(gb1 + ko,      &SL[nb + lo + 512]);
            GLDS16(gb0 + ko + 32, &SL[nb + 4096 + lo]); GLDS16(gb1 + ko + 32, &SL[nb + 4096 + lo + 512]);
        }
        for (int h = 0; h < 2; h++) {
            bf16x8 af[4], bfr[4];
            for (int i = 0; i < 4; i++) {
                af[i]  = *(const bf16x8*)&SL[ab + h * 4096 + (wm * 64 + i * 16 + l15) * 32 + quad * 8];
                bfr[i] = *(const bf16x8*)&SL[bb + h * 4096 + (wn * 64 + i * 16 + l15) * 32 + quad * 8];
            }
            for (int mi = 0; mi < 4; mi++)
                for (int ni = 0; ni < 4; ni++)
                    acc[mi][ni] = mfma16(af[mi], bfr[ni], acc[mi][ni]);
        }
    }
    asm volatile("" ::: "memory");

    if constexpr (F32OUT) {
        for (int ni = 0; ni < 4; ni++) {
            int col = n0 + wn * 64 + ni * 16 + l15;
            float bv = bias[col];
            for (int mi = 0; mi < 4; mi++) {
                int rowm = m0 + wm * 64 + mi * 16 + quad * 4;
                for (int r = 0; r < 4; r++) {
                    int m = rowm + r;
                    if (m < NROWS)
                        ((float*)outp)[(size_t)m * Ncols + col] = acc[mi][ni][r] + bv;
                }
            }
        }
    } else {
        // repack 128x128 bf16 tile (stride 132 u16) in LDS
        __syncthreads();
        for (int ni = 0; ni < 4; ni++) {
            int colL = wn * 64 + ni * 16 + l15;
            float bv = bias[n0 + colL];
            for (int mi = 0; mi < 4; mi++) {
                int rowL = wm * 64 + mi * 16 + quad * 4;
                for (int r = 0; r < 4; r++)
                    SL[(rowL + r) * 132 + colL] = f2bf(acc[mi][ni][r] + bv);
            }
        }
        __syncthreads();
        if (n0 < 1536) {
            // Q/K cols: full-line row stores to qkvb
            for (int rr = 0; rr < 8; rr++) {
                int row = rr * 16 + (t >> 4);
                int m = m0 + row;
                if (m < NROWS) {
                    uint4 v = *(uint4*)&SL[row * 132 + (t & 15) * 8];
                    *(uint4*)&((unsigned short*)outp)[(size_t)m * Ncols + n0 + (t & 15) * 8] = v;
                }
            }
        } else {
            // V cols: transposed store direct into vt[((b*12+h)*64+d)*NPAD + tok]
            int h0 = (n0 - 1536) >> 6;
            for (int i = 0; i < 32; i++) {
                int c = wave * 32 + i;
                int h = h0 + (c >> 6), d = c & 63;
                for (int half = 0; half < 2; half++) {
                    int lr = half * 64 + lane;
                    int m = m0 + lr;
                    if (m < NROWS) {
                        unsigned bbx = (unsigned)m / 577u;
                        int tok = m - (int)bbx * 577;
                        vt[(((size_t)bbx * NHEAD + h) * 64 + d) * NPAD + tok] =
                            SL[lr * 132 + c];
                    }
                }
            }
        }
    }
}

// --------------------------------------------------------- flash attention
// 128 q-rows per block; Q-frags direct global->VGPR; no max-subtraction
// (scores bounded); row-sum via ones-MFMA. Pad-token V is unwritten poison,
// but P==0 exactly there (pol=0, bf16 trunc) so PV is unaffected.
__global__ __launch_bounds__(256, 4)
void k_attn(const unsigned short* __restrict__ qkv, const unsigned short* __restrict__ vt,
            const float* __restrict__ policy, unsigned short* __restrict__ ao) {
    __shared__ unsigned short Ks[64 * 72];
    __shared__ unsigned short Vs[64 * 72];
    __shared__ unsigned short Ps[4][32 * 72];
    __shared__ float pol[NPAD];
    int t = threadIdx.x;
    int lane = t & 63, wave = t >> 6, quad = lane >> 4, l15 = lane & 15;
    int b = blockIdx.z, h = blockIdx.y, qt = blockIdx.x;
    const unsigned short* qbase = qkv + (size_t)(b * NTOK) * QKVC + h * 64;
    const unsigned short* kbase = qkv + (size_t)(b * NTOK) * QKVC + 768 + h * 64;
    const unsigned short* vbase = vt + (size_t)(b * NHEAD + h) * 64 * NPAD;

    for (int i = t; i < NPAD; i += 256)
        pol[i] = (i < NTOK) ? policy[b * NTOK + i] : 0.f;

    bf16x8 qf[2][2];
    for (int mi = 0; mi < 2; mi++) {
        const unsigned short* qp =
            qbase + (size_t)(qt * 128 + mi * 64 + wave * 16 + l15) * QKVC + quad * 8;
        qf[mi][0] = *(const bf16x8*)qp;
        qf[mi][1] = *(const bf16x8*)(qp + 32);
    }
    bf16x8 onesf;
    for (int j = 0; j < 8; j++) onesf[j] = (__bf16)1.0f;
    f32x4 o[2][4] = {};
    f32x4 ls[2] = {};
    int rowtok0[2];
    for (int mi = 0; mi < 2; mi++)
        rowtok0[mi] = qt * 128 + mi * 64 + wave * 16 + quad * 4;
    __syncthreads();

    for (int kt = 0; kt < 10; kt++) {
        int key0 = kt * 64;
        for (int i = t; i < 512; i += 256) {
            int row = i >> 3, seg = (i & 7) * 8;
            *(uint4*)&Ks[row * 72 + seg] = *(const uint4*)&kbase[(size_t)(key0 + row) * QKVC + seg];
            *(uint4*)&Vs[row * 72 + seg] = *(const uint4*)&vbase[(size_t)row * NPAD + key0 + seg];
        }
        __syncthreads();

        for (int ci = 0; ci < 4; ci++) {
            bf16x8 kf0 = *(const bf16x8*)&Ks[(ci * 16 + l15) * 72 + quad * 8];
            bf16x8 kf1 = *(const bf16x8*)&Ks[(ci * 16 + l15) * 72 + 32 + quad * 8];
            int col = key0 + ci * 16 + l15;
            float pc = pol[col];
            for (int mi = 0; mi < 2; mi++) {
                f32x4 a = {};
                a = mfma16(qf[mi][0], kf0, a);
                a = mfma16(qf[mi][1], kf1, a);
                for (int r = 0; r < 4; r++) {
                    float ap = (col == rowtok0[mi] + r) ? 1.f : pc;
                    float e = __expf(a[r] * SCALE) * ap;
                    Ps[wave][(mi * 16 + quad * 4 + r) * 72 + ci * 16 + l15] = f2bf_trunc(e);
                }
            }
        }
        __asm__ volatile("s_waitcnt lgkmcnt(0)" ::: "memory");
        bf16x8 pf[2][2];
        for (int mi = 0; mi < 2; mi++) {
            pf[mi][0] = *(const bf16x8*)&Ps[wave][(mi * 16 + l15) * 72 + quad * 8];
            pf[mi][1] = *(const bf16x8*)&Ps[wave][(mi * 16 + l15) * 72 + 32 + quad * 8];
            ls[mi] = mfma16(pf[mi][0], onesf, ls[mi]);
            ls[mi] = mfma16(pf[mi][1], onesf, ls[mi]);
        }
        for (int di = 0; di < 4; di++) {
            bf16x8 vf0 = *(const bf16x8*)&Vs[(di * 16 + l15) * 72 + quad * 8];
            bf16x8 vf1 = *(const bf16x8*)&Vs[(di * 16 + l15) * 72 + 32 + quad * 8];
            for (int mi = 0; mi < 2; mi++) {
                o[mi][di] = mfma16(pf[mi][0], vf0, o[mi][di]);
                o[mi][di] = mfma16(pf[mi][1], vf1, o[mi][di]);
            }
        }
        __syncthreads();
    }

    for (int mi = 0; mi < 2; mi++) {
        for (int r = 0; r < 4; r++) {
            int tok = rowtok0[mi] + r;
            if (tok < NTOK) {
                float inv = __builtin_amdgcn_rcpf(ls[mi][r] + EPSV);
                for (int di = 0; di < 4; di++) {
                    float val = o[mi][di][r] * inv;
                    ao[((size_t)(b * NTOK + tok)) * 768 + h * 64 + di * 16 + l15] = f2bf(val);
                }
            }
        }
    }
}

// ------------------------------------------------------------------ launch
extern "C" void kernel_launch(void* const* d_in, const int* in_sizes, int n_in,
                              void* d_out, int out_size, void* d_ws, size_t ws_size,
                              hipStream_t stream) {
    const float* x      = (const float*)d_in[0];
    const float* policy = (const float*)d_in[1];
    const float* Wqkv   = (const float*)d_in[2];
    const float* bqkv   = (const float*)d_in[3];
    const float* Wproj  = (const float*)d_in[4];
    const float* bproj  = (const float*)d_in[5];
    float* out = (float*)d_out;

    // workspace carve. xb/ao alias (xb dead before ao written). GEMM A-staging
    // over-reads up to ~1.5MB past xb/ao end (absorbed by wqkvt+wprojt);
    // attention Q/K over-reads <=300KB past qkvb (absorbed by vt).
    unsigned short* p = (unsigned short*)d_ws;
    unsigned short* xb     = p;
    unsigned short* ao     = p; p += (size_t)NROWS * 768;
    unsigned short* wqkvt  = p; p += (size_t)QKVC * 768;
    unsigned short* wprojt = p; p += (size_t)768 * 768;
    unsigned short* qkvb   = p; p += (size_t)NROWS * QKVC;
    unsigned short* vt     = p; p += (size_t)NBATCH * NHEAD * 64 * NPAD;

    int mT = (NROWS + 127) / 128;   // 73
    int mG = (mT + 7) / 8;          // 10 groups of 8 m-tiles (XCD stripes)

    k_prep<<<NCONV + 432 + 144, 256, 0, stream>>>(x, xb, Wqkv, wqkvt, Wproj, wprojt);
    k_gemm<false><<<mG * 8 * (QKVC / 128), 256, 0, stream>>>(
        xb, wqkvt, bqkv, (void*)qkvb, QKVC, vt);
    k_attn<<<dim3(NPAD / 128, NHEAD, NBATCH), 256, 0, stream>>>(qkvb, vt, policy, ao);
    k_gemm<true><<<mG * 8 * (768 / 128), 256, 0, stream>>>(
        ao, wprojt, bproj, (void*)out, 768, nullptr);
}